// Round 9
// baseline (162.595 us; speedup 1.0000x reference)
//
#include <hip/hip_runtime.h>
#include <math.h>

#define B_ 32
#define T_ 4096
#define D_ 256
#define C_ 64
#define EPSN 1e-6f
#define EPSG 1e-6f
#define EPSL 1e-5f
#define DS_ 0.1f

typedef short bfrag __attribute__((ext_vector_type(8)));      // 8 bf16 = 4 VGPR
typedef float f32x4 __attribute__((ext_vector_type(4)));
typedef unsigned short ushort4_t __attribute__((ext_vector_type(4)));
typedef unsigned short ushort8_t __attribute__((ext_vector_type(8)));

static __device__ __forceinline__ unsigned short f2bf(float f) {
    unsigned int u = __builtin_bit_cast(unsigned int, f);
    unsigned int r = u + 0x7fffu + ((u >> 16) & 1u);
    return (unsigned short)(r >> 16);
}
static __device__ __forceinline__ float bf2f(unsigned short u) {
    return __builtin_bit_cast(float, ((unsigned int)u) << 16);
}

static __device__ __forceinline__ f32x4 mfma_bf16(bfrag a, bfrag b, f32x4 c) {
    return __builtin_amdgcn_mfma_f32_16x16x32_bf16(a, b, c, 0, 0, 0);
}

static __device__ __forceinline__ bfrag cvt8(float4 lo, float4 hi) {
    bfrag v;
    v[0] = (short)f2bf(lo.x); v[1] = (short)f2bf(lo.y);
    v[2] = (short)f2bf(lo.z); v[3] = (short)f2bf(lo.w);
    v[4] = (short)f2bf(hi.x); v[5] = (short)f2bf(hi.y);
    v[6] = (short)f2bf(hi.z); v[7] = (short)f2bf(hi.w);
    return v;
}

// async global->LDS, 16B per lane, LDS dest = wave-uniform base + lane*16
static __device__ __forceinline__ void gload_lds16(const float* g, float* l) {
    __builtin_amdgcn_global_load_lds(
        (const __attribute__((address_space(1))) unsigned int*)(g),
        (__attribute__((address_space(3))) unsigned int*)(l), 16, 0, 0);
}

// ===================== Kernel P: prepack weights -> bf16 fragment-layout images =====================
__global__ __launch_bounds__(256) void prepack_kernel(
    const float* __restrict__ w_in,
    const float* __restrict__ wd0, const float* __restrict__ wp0,
    const float* __restrict__ wd1, const float* __restrict__ wp1,
    const float* __restrict__ wd2, const float* __restrict__ wp2,
    unsigned short* __restrict__ wk)
{
    int idx = blockIdx.x * 256 + threadIdx.x;
    if (idx >= 1024 + 3 * 16384) return;
    if (idx < 1024) {
        int c = idx >> 4, a = idx & 15;
        float wv = 0.f;
        if (a <= 8) {
            wv = w_in[c * 17 + 8 + a];
            if (a > 0) wv += w_in[c * 17 + 8 - a];
        }
        wk[idx] = f2bf(wv);
    } else {
        int i2 = idx - 1024;
        int s = i2 >> 14;
        int r = i2 & 16383;
        const float* wd = s == 0 ? wd0 : (s == 1 ? wd1 : wd2);
        const float* wp = s == 0 ? wp0 : (s == 1 ? wp1 : wp2);
        unsigned short v;
        if (r < 12288) {
            int c = r / 192, k = r - c * 192;
            int tap = k >> 6, ci = k & 63;
            v = f2bf(wd[c * 192 + ci * 3 + tap]);
        } else {
            v = f2bf(wp[r - 12288]);
        }
        wk[idx] = v;
    }
}

// ===================== Kernel A: Gram-band strip, whole-tile async-LDS, 2-phase =====================
// Block: 4 waves, 104 staged rows (96 outputs + 8 halo), f32 in LDS via global_load_lds.
// Source pre-swizzled (16B slot s of row r holds global slot s^(r&7)); reads use same XOR.
// Two K-halves (128 f32) double-buffered: issue all 26 loads/wave, vmcnt(13) -> compute h0,
// vmcnt(0) -> compute h1. Per wave: 3-tile diag group T00/T01/T11; self-dots = diagonals.
#define NT24 43            // ceil(4096 / 96)
#define XHALF 13312        // 104 * 128 f32 per half-buffer
#define SMEM_STRIP (30288 * 4)   // xbuf 2*13312 + dotbuf 3456 + scl 104 + msk 104 f32

__global__ __launch_bounds__(256) void strip_kernel(
    const float* __restrict__ feat0, const float* __restrict__ mask0,
    const float* __restrict__ feat1, const float* __restrict__ mask1,
    unsigned short* __restrict__ s16g)     // [2*B][T][16] bf16, slots 0..8 = bands, 9..15 = 0
{
    extern __shared__ float sm[];
    float* xbuf   = sm;              // [2][104][128]
    float* dotbuf = sm + 26624;      // [4][3*16*18]
    float* scl    = sm + 30080;      // [104]
    float* msk    = sm + 30184;      // [104]

    int bid0 = blockIdx.x;                        // 2752 = 8 * 344
    int bid  = (bid0 & 7) * 344 + (bid0 >> 3);    // XCD-chunked bijective swizzle
    int tile = bid % NT24;
    int rem  = bid / NT24;
    int b    = rem & 31;
    int mod  = rem >> 5;
    int mb   = mod * B_ + b;
    const float* feat = mod ? feat1 : feat0;
    const float* mask = mod ? mask1 : mask0;
    int t0 = tile * 96;
    int tid = threadIdx.x;
    int w = tid >> 6, lane = tid & 63;
    int l15 = lane & 15, lg = lane >> 4;

    const float* fb = feat + (size_t)b * T_ * D_;

    // ---- async stage of one K-half: 13 x 1KB per wave (2 rows per instruction)
    auto stage_half = [&](int h, float* buf) {
        #pragma unroll
        for (int i = 0; i < 13; ++i) {
            int gi = w * 13 + i;
            int row = gi * 2 + (lane >> 5);
            int tg = t0 + row; if (tg >= T_) tg = T_ - 1;   // clamped rows masked later
            const float* gp = fb + (size_t)tg * D_ + h * 128
                              + (((lane & 31) ^ (row & 7)) << 2);
            gload_lds16(gp, buf + gi * 256);
        }
    };

    int rA = 24 * w + l15;       // local rows
    int rB = rA + 16;
    int a7 = rA & 7, b7 = rB & 7;
    f32x4 a00 = {0.f, 0.f, 0.f, 0.f};
    f32x4 a01 = {0.f, 0.f, 0.f, 0.f};
    f32x4 a11 = {0.f, 0.f, 0.f, 0.f};

    auto compute_half = [&](const float* xb) {
        const float* pa = xb + rA * 128;
        const float* pb = xb + rB * 128;
        #pragma unroll
        for (int ks = 0; ks < 4; ++ks) {
            int s0 = ks * 8 + lg * 2;
            float4 a0 = *(const float4*)(pa + ((s0 ^ a7) << 2));
            float4 a1 = *(const float4*)(pa + (((s0 + 1) ^ a7) << 2));
            float4 b0 = *(const float4*)(pb + ((s0 ^ b7) << 2));
            float4 b1 = *(const float4*)(pb + (((s0 + 1) ^ b7) << 2));
            bfrag av = cvt8(a0, a1);
            bfrag bv = cvt8(b0, b1);
            a00 = mfma_bf16(av, av, a00);
            a01 = mfma_bf16(av, bv, a01);
            a11 = mfma_bf16(bv, bv, a11);
        }
    };

    // ---- pipeline: issue both halves, counted waits, 2 barriers total
    stage_half(0, xbuf);
    stage_half(1, xbuf + XHALF);

    asm volatile("s_waitcnt vmcnt(13)" ::: "memory");   // own h0 loads done
    __builtin_amdgcn_sched_barrier(0);
    __builtin_amdgcn_s_barrier();                       // all waves' h0 staged
    compute_half(xbuf);

    asm volatile("s_waitcnt vmcnt(0)" ::: "memory");    // own h1 loads done
    __builtin_amdgcn_sched_barrier(0);
    __builtin_amdgcn_s_barrier();                       // all waves' h1 staged
    compute_half(xbuf + XHALF);

    // ---- publish dots (T00 | T01 | T11, pitch 18) + mask
    {
        float* base = dotbuf + w * 864;
        #pragma unroll
        for (int r = 0; r < 4; ++r) {
            int row = lg * 4 + r;
            base[row * 18 + l15] = a00[r];
            base[288 + row * 18 + l15] = a01[r];
            base[576 + row * 18 + l15] = a11[r];
        }
    }
    if (tid < 104) {
        int tg = t0 + tid;
        msk[tid] = (tg < T_) ? mask[(size_t)b * T_ + tg] : 0.f;
    }
    __syncthreads();

    // ---- scl[t] = m / (m*sqrt(selfdot) + eps) from T00/T11 diagonals (covers all 104 rows)
    if (tid < 104) {
        int ww = tid / 24; if (ww > 3) ww = 3;
        int v = tid - 24 * ww;
        const float* bb = dotbuf + ww * 864;
        float sd = (v < 16) ? bb[v * 18 + v] : bb[576 + (v - 16) * 18 + (v - 16)];
        float m = msk[tid];
        scl[tid] = m / (m * sqrtf(sd) + EPSN);
    }
    __syncthreads();

    // ---- band extraction + bf16 pack (threads 0..95 = output rows)
    if (tid < 96) {
        int t = t0 + tid;
        if (t < T_) {
            int ww = tid / 24, r = tid - 24 * ww;
            const float* bb = dotbuf + ww * 864;
            float m_t = msk[tid], sc_t = scl[tid];
            ushort8_t o0, o1;
            #pragma unroll
            for (int e = 0; e < 8; ++e) { o0[e] = 0; o1[e] = 0; }
            #pragma unroll
            for (int a = 0; a <= 8; ++a) {
                int c = r + a;
                float dot;
                if (r < 8)       dot = bb[r * 18 + c];
                else if (r < 16) dot = (c < 16) ? bb[r * 18 + c]
                                               : bb[288 + r * 18 + (c - 16)];
                else             dot = bb[576 + (r - 16) * 18 + (c - 16)];
                float dn = dot * sc_t * scl[tid + a];
                float s = (dn - (a == 0 ? DS_ : 0.f) + 1.f) * 0.5f * m_t * msk[tid + a];
                if (a < 8) o0[a] = f2bf(s); else o1[0] = f2bf(s);
            }
            unsigned short* dst = s16g + ((size_t)mb * T_ + t) * 16;
            *(ushort8_t*)dst = o0;
            *(ushort8_t*)(dst + 8) = o1;
        }
    }
}

// ===================== Kernel B: MFMA conv stack + masked GAP partials =====================
#define TT 128
#define G_ 16
#define WB 160            // TT + 2*G_
#define SBP 24            // sbuf pitch (48B rows: 16B-aligned, conflict-free)
#define OFF_BUFA 8192
#define OFF_BUFB 28672
#define OFF_MLD  49664
#define OFF_RED  50176
#define SMEM_TOT (OFF_RED + 1024)

// swizzled ushort index: 16B slot su (0..7) of row, XOR'd by row&7; off = ushort offset in slot
static __device__ __forceinline__ int swzi(int row, int su, int off) {
    return row * 64 + ((su ^ (row & 7)) << 3) + off;
}

template<int DIL>
static __device__ __forceinline__ void conv_stage(
    const unsigned short* __restrict__ wdg, const unsigned short* __restrict__ wpg,
    unsigned short* __restrict__ bufIn, unsigned short* __restrict__ bufOut,
    const float* __restrict__ b_d, const float* __restrict__ b_p,
    int t0, int l15, int lg, int mt0, int wn)
{
    // ---- dilated 3-tap conv as K=192 GEMM (k = tap*64 + ci), bufIn -> bufOut
    {
        bfrag ad[2][6];
        float bd[2][4];
        #pragma unroll
        for (int m = 0; m < 2; ++m) {
            int row = (mt0 + m) * 16 + l15;
            #pragma unroll
            for (int ks = 0; ks < 6; ++ks) {
                int tap = ks >> 1, half = ks & 1;
                ad[m][ks] = *(const bfrag*)(wdg + row * 192 + tap * 64 + half * 32 + lg * 8);
            }
            #pragma unroll
            for (int r = 0; r < 4; ++r) bd[m][r] = b_d[(mt0 + m) * 16 + lg * 4 + r];
        }
        for (int nt = wn * 5; nt < wn * 5 + 5; ++nt) {
            int j = nt * 16 + l15;
            f32x4 acc0 = {0.f, 0.f, 0.f, 0.f}, acc1 = {0.f, 0.f, 0.f, 0.f};
            #pragma unroll
            for (int ks = 0; ks < 6; ++ks) {
                int tap = ks >> 1, half = ks & 1;
                int brow = j + (tap - 1) * DIL;
                bfrag bv = *(const bfrag*)(bufIn + swzi(brow, half * 4 + lg, 0));
                acc0 = mfma_bf16(ad[0][ks], bv, acc0);
                acc1 = mfma_bf16(ad[1][ks], bv, acc1);
            }
            int tg = t0 - G_ + j;
            bool valid = (tg >= 0 && tg < T_);
            #pragma unroll
            for (int m = 0; m < 2; ++m) {
                f32x4 acc = m ? acc1 : acc0;
                ushort4_t pk;
                #pragma unroll
                for (int r = 0; r < 4; ++r) {
                    float v = acc[r] + bd[m][r];
                    v = valid ? fmaxf(v, 0.f) : 0.f;
                    pk[r] = f2bf(v);
                }
                *(ushort4_t*)(bufOut + swzi(j, (mt0 + m) * 2 + (lg >> 1), (lg & 1) * 4)) = pk;
            }
        }
    }
    __syncthreads();

    // ---- pointwise conv as K=64 GEMM, bufOut -> bufIn
    {
        bfrag ap[2][2];
        float bpv[2][4];
        #pragma unroll
        for (int m = 0; m < 2; ++m) {
            int row = (mt0 + m) * 16 + l15;
            #pragma unroll
            for (int half = 0; half < 2; ++half)
                ap[m][half] = *(const bfrag*)(wpg + row * 64 + half * 32 + lg * 8);
            #pragma unroll
            for (int r = 0; r < 4; ++r) bpv[m][r] = b_p[(mt0 + m) * 16 + lg * 4 + r];
        }
        for (int nt = wn * 5; nt < wn * 5 + 5; ++nt) {
            int j = nt * 16 + l15;
            f32x4 acc0 = {0.f, 0.f, 0.f, 0.f}, acc1 = {0.f, 0.f, 0.f, 0.f};
            #pragma unroll
            for (int half = 0; half < 2; ++half) {
                bfrag bv = *(const bfrag*)(bufOut + swzi(j, half * 4 + lg, 0));
                acc0 = mfma_bf16(ap[0][half], bv, acc0);
                acc1 = mfma_bf16(ap[1][half], bv, acc1);
            }
            int tg = t0 - G_ + j;
            bool valid = (tg >= 0 && tg < T_);
            #pragma unroll
            for (int m = 0; m < 2; ++m) {
                f32x4 acc = m ? acc1 : acc0;
                ushort4_t pk;
                #pragma unroll
                for (int r = 0; r < 4; ++r) {
                    float v = acc[r] + bpv[m][r];
                    v = valid ? fmaxf(v, 0.f) : 0.f;
                    pk[r] = f2bf(v);
                }
                *(ushort4_t*)(bufIn + swzi(j, (mt0 + m) * 2 + (lg >> 1), (lg & 1) * 4)) = pk;
            }
        }
    }
    __syncthreads();
}

__global__ __launch_bounds__(256, 3) void conv_mfma_kernel(
    const unsigned short* __restrict__ s16g,
    const float* __restrict__ mask0, const float* __restrict__ mask1,
    const unsigned short* __restrict__ wk,
    const float* __restrict__ b_in,
    const float* __restrict__ b_d1, const float* __restrict__ b_p1,
    const float* __restrict__ b_d2, const float* __restrict__ b_p2,
    const float* __restrict__ b_d3, const float* __restrict__ b_p3,
    float* __restrict__ z_part)        // [2*B][32][64]
{
    __shared__ __align__(16) char smem[SMEM_TOT];
    unsigned short* sbuf = (unsigned short*)smem;                 // [WB][SBP]
    unsigned short* bufA = (unsigned short*)(smem + OFF_BUFA);
    unsigned short* bufB = (unsigned short*)(smem + OFF_BUFB);
    float* mld = (float*)(smem + OFF_MLD);                        // [TT]
    float* red = (float*)(smem + OFF_RED);                        // [4][64]

    int bid  = blockIdx.x;                             // 2*B*32 = 2048
    int tile = bid & 31;
    int b    = (bid >> 5) & 31;
    int mod  = bid >> 10;
    int mb   = mod * B_ + b;
    const float* mask = mod ? mask1 : mask0;
    int t0  = tile * TT;
    int tid = threadIdx.x;
    int lane = tid & 63;
    int w = tid >> 6;
    int l15 = lane & 15, lg = lane >> 4;
    int wm = w >> 1, wn = w & 1;
    int mt0 = wm * 2;

    const unsigned short* weff_g = wk;

    // ---- stage s16 tile (with t-bounds zero fill) + mask
    {
        const unsigned short* srow = s16g + (size_t)mb * T_ * 16;
        for (int ch = tid; ch < WB * 2; ch += 256) {
            int j = ch >> 1, q = ch & 1;
            int t = t0 - G_ + j;
            ushort8_t v = {0, 0, 0, 0, 0, 0, 0, 0};
            if (t >= 0 && t < T_) v = *(const ushort8_t*)(srow + (size_t)t * 16 + q * 8);
            *(ushort8_t*)(sbuf + j * SBP + q * 8) = v;
        }
        if (tid < TT) {
            int tg = t0 + tid;
            mld[tid] = (tg < T_) ? mask[(size_t)b * T_ + tg] : 0.f;
        }
    }
    __syncthreads();

    // ---- in-conv (K=9 padded into one masked K=32 MFMA step) -> bufA
    {
        int lg2 = lg & 1;
        bfrag a_in[2];
        float bi[2][4];
        #pragma unroll
        for (int m = 0; m < 2; ++m) {
            int row = (mt0 + m) * 16 + l15;
            a_in[m] = *(const bfrag*)(weff_g + row * 16 + lg2 * 8);
            #pragma unroll
            for (int r = 0; r < 4; ++r) bi[m][r] = b_in[(mt0 + m) * 16 + lg * 4 + r];
        }
        for (int nt = wn * 5; nt < wn * 5 + 5; ++nt) {
            int j = nt * 16 + l15;
            bfrag bv = {0, 0, 0, 0, 0, 0, 0, 0};
            if (lg < 2) bv = *(const bfrag*)(sbuf + j * SBP + lg * 8);
            f32x4 acc0 = {0.f, 0.f, 0.f, 0.f}, acc1 = {0.f, 0.f, 0.f, 0.f};
            acc0 = mfma_bf16(a_in[0], bv, acc0);
            acc1 = mfma_bf16(a_in[1], bv, acc1);
            int tg = t0 - G_ + j;
            bool valid = (tg >= 0 && tg < T_);
            #pragma unroll
            for (int m = 0; m < 2; ++m) {
                f32x4 acc = m ? acc1 : acc0;
                ushort4_t pk;
                #pragma unroll
                for (int r = 0; r < 4; ++r) {
                    float v = acc[r] + bi[m][r];
                    v = valid ? fmaxf(v, 0.f) : 0.f;
                    pk[r] = f2bf(v);
                }
                *(ushort4_t*)(bufA + swzi(j, (mt0 + m) * 2 + (lg >> 1), (lg & 1) * 4)) = pk;
            }
        }
    }
    __syncthreads();

    conv_stage<1>(wk + 1024,             wk + 1024 + 12288,             bufA, bufB, b_d1, b_p1, t0, l15, lg, mt0, wn);
    conv_stage<2>(wk + 1024 + 16384,     wk + 1024 + 16384 + 12288,     bufA, bufB, b_d2, b_p2, t0, l15, lg, mt0, wn);
    conv_stage<4>(wk + 1024 + 2 * 16384, wk + 1024 + 2 * 16384 + 12288, bufA, bufB, b_d3, b_p3, t0, l15, lg, mt0, wn);

    // ---- masked GAP partial over this tile's 128 cols (j in [G_, G_+TT))
    {
        int c = tid & 63, g = tid >> 6;
        float acc = 0.f;
        #pragma unroll 4
        for (int i = 0; i < 32; ++i) {
            int jj = g * 32 + i;
            int r = G_ + jj;
            acc += bf2f(bufA[swzi(r, c >> 3, c & 7)]) * mld[jj];
        }
        red[g * 64 + c] = acc;
    }
    __syncthreads();
    if (tid < 64) {
        float z = red[tid] + red[64 + tid] + red[128 + tid] + red[192 + tid];
        z_part[((size_t)mb * 32 + tile) * 64 + tid] = z;
    }
}

// ===================== Kernel C: GAP divide + LayerNorm + gates =====================
__global__ __launch_bounds__(128) void gates_kernel(
    const float* __restrict__ z_part,
    const float* __restrict__ mask0, const float* __restrict__ mask1,
    const float* __restrict__ ln_g, const float* __restrict__ ln_b,
    const float* __restrict__ mha_w1, const float* __restrict__ mha_b1,
    const float* __restrict__ mha_w2, const float* __restrict__ mha_b2,
    const float* __restrict__ ffn_w1, const float* __restrict__ ffn_b1,
    const float* __restrict__ ffn_w2, const float* __restrict__ ffn_b2,
    float* __restrict__ out)
{
    __shared__ float fn[128];
    __shared__ float red[4];
    __shared__ float msum[2];
    int b = blockIdx.x, tid = threadIdx.x;
    int mod = tid >> 6, c = tid & 63;

    float z = 0.f;
    for (int tl = 0; tl < 32; ++tl)
        z += z_part[((size_t)(mod * B_ + b) * 32 + tl) * 64 + c];

    const float* mk = mod ? mask1 : mask0;
    float ms = 0.f;
    for (int t = c; t < T_; t += 64) ms += mk[(size_t)b * T_ + t];
    #pragma unroll
    for (int o = 32; o > 0; o >>= 1) ms += __shfl_xor(ms, o);
    if (c == 0) msum[mod] = ms;
    __syncthreads();

    float fv = z / (msum[mod] + EPSG);
    float s1 = fv, s2 = fv * fv;
    #pragma unroll
    for (int o = 32; o > 0; o >>= 1) { s1 += __shfl_xor(s1, o); s2 += __shfl_xor(s2, o); }
    if (c == 0) { red[mod * 2] = s1; red[mod * 2 + 1] = s2; }
    __syncthreads();

    float mu  = (red[0] + red[2]) * (1.0f / 128.0f);
    float ex2 = (red[1] + red[3]) * (1.0f / 128.0f);
    float var = ex2 - mu * mu;
    float fnv = (fv - mu) * rsqrtf(var + EPSL) * ln_g[tid] + ln_b[tid];
    fn[tid] = fnv;
    __syncthreads();

    const float* W1 = mod ? ffn_w1 : mha_w1;
    const float* B1 = mod ? ffn_b1 : mha_b1;
    const float* W2 = mod ? ffn_w2 : mha_w2;
    const float* B2 = mod ? ffn_b2 : mha_b2;
    float r = B1[c];
    for (int i = 0; i < 128; ++i) r += fn[i] * W1[i * 64 + c];
    r = fmaxf(r, 0.f);
    float g = r * W2[c];
    #pragma unroll
    for (int o = 32; o > 0; o >>= 1) g += __shfl_xor(g, o);
    if (c == 0) {
        g += B2[0];
        out[mod * B_ + b] = mod ? tanhf(g) : 1.0f / (1.0f + expf(-g));
    }
}

// ===================== launch =====================
extern "C" void kernel_launch(void* const* d_in, const int* in_sizes, int n_in,
                              void* d_out, int out_size, void* d_ws, size_t ws_size,
                              hipStream_t stream) {
    const float* video_feat = (const float*)d_in[0];
    const float* audio_feat = (const float*)d_in[1];
    const float* video_mask = (const float*)d_in[2];
    const float* audio_mask = (const float*)d_in[3];
    const float* w_in = (const float*)d_in[4];
    const float* b_in = (const float*)d_in[5];
    const float* w_d1 = (const float*)d_in[6];
    const float* b_d1 = (const float*)d_in[7];
    const float* w_p1 = (const float*)d_in[8];
    const float* b_p1 = (const float*)d_in[9];
    const float* w_d2 = (const float*)d_in[10];
    const float* b_d2 = (const float*)d_in[11];
    const float* w_p2 = (const float*)d_in[12];
    const float* b_p2 = (const float*)d_in[13];
    const float* w_d3 = (const float*)d_in[14];
    const float* b_d3 = (const float*)d_in[15];
    const float* w_p3 = (const float*)d_in[16];
    const float* b_p3 = (const float*)d_in[17];
    const float* ln_g = (const float*)d_in[18];
    const float* ln_b = (const float*)d_in[19];
    const float* mha_w1 = (const float*)d_in[20];
    const float* mha_b1 = (const float*)d_in[21];
    const float* mha_w2 = (const float*)d_in[22];
    const float* mha_b2 = (const float*)d_in[23];
    const float* ffn_w1 = (const float*)d_in[24];
    const float* ffn_b1 = (const float*)d_in[25];
    const float* ffn_w2 = (const float*)d_in[26];
    const float* ffn_b2 = (const float*)d_in[27];

    unsigned short* s16g = (unsigned short*)d_ws;                          // 2*B*T*16 bf16 = 8.39 MB
    float* z_part = (float*)((char*)d_ws + (size_t)2 * B_ * T_ * 16 * 2);  // 2*B*32*64 f32 = 512 KB
    unsigned short* wk = (unsigned short*)((char*)z_part + (size_t)2 * B_ * 32 * 64 * 4);  // 100 KB

    prepack_kernel<<<dim3(196), dim3(256), 0, stream>>>(
        w_in, w_d1, w_p1, w_d2, w_p2, w_d3, w_p3, wk);

    hipFuncSetAttribute((const void*)strip_kernel,
                        hipFuncAttributeMaxDynamicSharedMemorySize, SMEM_STRIP);
    strip_kernel<<<dim3(2 * B_ * NT24), dim3(256), SMEM_STRIP, stream>>>(
        audio_feat, audio_mask, video_feat, video_mask, s16g);

    conv_mfma_kernel<<<dim3(2 * B_ * (T_ / TT)), dim3(256), 0, stream>>>(
        s16g, audio_mask, video_mask, wk, b_in,
        b_d1, b_p1, b_d2, b_p2, b_d3, b_p3, z_part);

    gates_kernel<<<dim3(B_), dim3(128), 0, stream>>>(
        z_part, audio_mask, video_mask, ln_g, ln_b,
        mha_w1, mha_b1, mha_w2, mha_b2, ffn_w1, ffn_b1, ffn_w2, ffn_b2,
        (float*)d_out);
}

// Round 10
// 145.108 us; speedup vs baseline: 1.1205x; 1.1205x over previous
//
#include <hip/hip_runtime.h>
#include <math.h>

#define B_ 32
#define T_ 4096
#define D_ 256
#define C_ 64
#define EPSN 1e-6f
#define EPSG 1e-6f
#define EPSL 1e-5f
#define DS_ 0.1f

typedef short bfrag __attribute__((ext_vector_type(8)));      // 8 bf16 = 4 VGPR
typedef float f32x4 __attribute__((ext_vector_type(4)));
typedef unsigned short ushort4_t __attribute__((ext_vector_type(4)));
typedef unsigned short ushort8_t __attribute__((ext_vector_type(8)));

static __device__ __forceinline__ unsigned short f2bf(float f) {
    unsigned int u = __builtin_bit_cast(unsigned int, f);
    unsigned int r = u + 0x7fffu + ((u >> 16) & 1u);
    return (unsigned short)(r >> 16);
}
static __device__ __forceinline__ float bf2f(unsigned short u) {
    return __builtin_bit_cast(float, ((unsigned int)u) << 16);
}

static __device__ __forceinline__ f32x4 mfma_bf16(bfrag a, bfrag b, f32x4 c) {
    return __builtin_amdgcn_mfma_f32_16x16x32_bf16(a, b, c, 0, 0, 0);
}

static __device__ __forceinline__ bfrag cvt8(float4 lo, float4 hi) {
    bfrag v;
    v[0] = (short)f2bf(lo.x); v[1] = (short)f2bf(lo.y);
    v[2] = (short)f2bf(lo.z); v[3] = (short)f2bf(lo.w);
    v[4] = (short)f2bf(hi.x); v[5] = (short)f2bf(hi.y);
    v[6] = (short)f2bf(hi.z); v[7] = (short)f2bf(hi.w);
    return v;
}

// forced-issue 16B load: asm volatile keeps program order and pins the result registers
#define GLD16(dst, base, OFF) \
    asm volatile("global_load_dwordx4 %0, %1, off offset:" #OFF \
                 : "=v"(dst) : "v"(base))

// ===================== Kernel P: prepack weights -> bf16 fragment-layout images =====================
__global__ __launch_bounds__(256) void prepack_kernel(
    const float* __restrict__ w_in,
    const float* __restrict__ wd0, const float* __restrict__ wp0,
    const float* __restrict__ wd1, const float* __restrict__ wp1,
    const float* __restrict__ wd2, const float* __restrict__ wp2,
    unsigned short* __restrict__ wk)
{
    int idx = blockIdx.x * 256 + threadIdx.x;
    if (idx >= 1024 + 3 * 16384) return;
    if (idx < 1024) {
        int c = idx >> 4, a = idx & 15;
        float wv = 0.f;
        if (a <= 8) {
            wv = w_in[c * 17 + 8 + a];
            if (a > 0) wv += w_in[c * 17 + 8 - a];
        }
        wk[idx] = f2bf(wv);
    } else {
        int i2 = idx - 1024;
        int s = i2 >> 14;
        int r = i2 & 16383;
        const float* wd = s == 0 ? wd0 : (s == 1 ? wd1 : wd2);
        const float* wp = s == 0 ? wp0 : (s == 1 ? wp1 : wp2);
        unsigned short v;
        if (r < 12288) {
            int c = r / 192, k = r - c * 192;
            int tap = k >> 6, ci = k & 63;
            v = f2bf(wd[c * 192 + ci * 3 + tap]);
        } else {
            v = f2bf(wp[r - 12288]);
        }
        wk[idx] = v;
    }
}

// ===================== Kernel A: MFMA Gram-band strip, 3-tile diag, asm-forced deep MLP =====================
// Block: 4 waves, each wave: rows i0..i0+31 -> tiles T00=(i0,i0), T01=(i0,i0+16), T11=(i0+16,i0+16),
// emitting band rows i0..i0+23. 32 inline-asm global_load_dwordx4 in flight per wave.
#define NT24 43            // ceil(4096 / 96) tiles per (mod,b)
#define DTP 18             // dotbuf pitch

__global__ __launch_bounds__(256, 2) void strip_kernel(
    const float* __restrict__ feat0, const float* __restrict__ mask0,
    const float* __restrict__ feat1, const float* __restrict__ mask1,
    unsigned short* __restrict__ s16g)     // [2*B][T][16] bf16, slots 0..8 = bands, 9..15 = 0
{
    __shared__ float dotbuf[4 * 3 * 16 * DTP];   // 13824 B
    __shared__ float scl[104];
    __shared__ float msk[104];

    int bid0 = blockIdx.x;                        // 2752 = 8 * 344
    int bid  = (bid0 & 7) * 344 + (bid0 >> 3);    // XCD-chunked bijective swizzle
    int tile = bid % NT24;
    int rem  = bid / NT24;
    int b    = rem & 31;
    int mod  = rem >> 5;
    int mb   = mod * B_ + b;
    const float* feat = mod ? feat1 : feat0;
    const float* mask = mod ? mask1 : mask0;
    int t0 = tile * 96;
    int tid = threadIdx.x;
    int w = tid >> 6, lane = tid & 63;
    int l15 = lane & 15, lg = lane >> 4;

    if (tid < 104) {
        int tg = t0 + tid;
        msk[tid] = (tg < T_) ? mask[(size_t)b * T_ + tg] : 0.f;
    }

    const float* fb = feat + (size_t)b * T_ * D_;

    // ---- per-wave 3-tile Gram group; 32 asm loads in flight before any convert
    {
        int i0 = t0 + 24 * w;
        int tA = i0 + l15;      if (tA >= T_) tA = 0;
        int tB = i0 + 16 + l15; if (tB >= T_) tB = 0;
        const float* pA = fb + (size_t)tA * D_ + lg * 8;
        const float* pB = fb + (size_t)tB * D_ + lg * 8;

        float4 fa[16], fbx[16];
        // K-step ks: lo at byte ks*128, hi at ks*128+16
        GLD16(fa[0],  pA, 0);    GLD16(fbx[0],  pB, 0);
        GLD16(fa[1],  pA, 16);   GLD16(fbx[1],  pB, 16);
        GLD16(fa[2],  pA, 128);  GLD16(fbx[2],  pB, 128);
        GLD16(fa[3],  pA, 144);  GLD16(fbx[3],  pB, 144);
        GLD16(fa[4],  pA, 256);  GLD16(fbx[4],  pB, 256);
        GLD16(fa[5],  pA, 272);  GLD16(fbx[5],  pB, 272);
        GLD16(fa[6],  pA, 384);  GLD16(fbx[6],  pB, 384);
        GLD16(fa[7],  pA, 400);  GLD16(fbx[7],  pB, 400);
        GLD16(fa[8],  pA, 512);  GLD16(fbx[8],  pB, 512);
        GLD16(fa[9],  pA, 528);  GLD16(fbx[9],  pB, 528);
        GLD16(fa[10], pA, 640);  GLD16(fbx[10], pB, 640);
        GLD16(fa[11], pA, 656);  GLD16(fbx[11], pB, 656);
        GLD16(fa[12], pA, 768);  GLD16(fbx[12], pB, 768);
        GLD16(fa[13], pA, 784);  GLD16(fbx[13], pB, 784);
        GLD16(fa[14], pA, 896);  GLD16(fbx[14], pB, 896);
        GLD16(fa[15], pA, 912);  GLD16(fbx[15], pB, 912);

        __builtin_amdgcn_sched_barrier(0);
        asm volatile("s_waitcnt vmcnt(0)" ::: "memory");
        __builtin_amdgcn_sched_barrier(0);

        f32x4 a00 = {0.f, 0.f, 0.f, 0.f};
        f32x4 a01 = {0.f, 0.f, 0.f, 0.f};
        f32x4 a11 = {0.f, 0.f, 0.f, 0.f};
        #pragma unroll
        for (int ks = 0; ks < 8; ++ks) {
            bfrag av = cvt8(fa[2 * ks], fa[2 * ks + 1]);
            bfrag bv = cvt8(fbx[2 * ks], fbx[2 * ks + 1]);
            a00 = mfma_bf16(av, av, a00);
            a01 = mfma_bf16(av, bv, a01);
            a11 = mfma_bf16(bv, bv, a11);
        }

        float* base = dotbuf + w * (3 * 16 * DTP);
        #pragma unroll
        for (int r = 0; r < 4; ++r) {
            int row = lg * 4 + r;
            base[row * DTP + l15] = a00[r];
            base[16 * DTP + row * DTP + l15] = a01[r];
            base[32 * DTP + row * DTP + l15] = a11[r];
        }
    }
    __syncthreads();

    // ---- scl[t] = m / (m*sqrt(selfdot) + eps) from T00/T11 diagonals
    if (tid < 104) {
        int ww = tid / 24; if (ww > 3) ww = 3;
        int v = tid - 24 * ww;
        const float* bb = dotbuf + ww * (3 * 16 * DTP);
        float sd = (v < 16) ? bb[v * DTP + v] : bb[32 * DTP + (v - 16) * DTP + (v - 16)];
        float m = msk[tid];
        scl[tid] = m / (m * sqrtf(sd) + EPSN);
    }
    __syncthreads();

    // ---- band extraction + bf16 pack (threads 0..95 = output rows)
    if (tid < 96) {
        int t = t0 + tid;
        if (t < T_) {
            int ww = tid / 24, r = tid - 24 * ww;
            const float* bb = dotbuf + ww * (3 * 16 * DTP);
            float m_t = msk[tid], sc_t = scl[tid];
            ushort8_t o0, o1;
            #pragma unroll
            for (int e = 0; e < 8; ++e) { o0[e] = 0; o1[e] = 0; }
            #pragma unroll
            for (int a = 0; a <= 8; ++a) {
                int c = r + a;
                float dot;
                if (r < 8)       dot = bb[r * DTP + c];
                else if (r < 16) dot = (c < 16) ? bb[r * DTP + c]
                                               : bb[16 * DTP + r * DTP + (c - 16)];
                else             dot = bb[32 * DTP + (r - 16) * DTP + (c - 16)];
                float dn = dot * sc_t * scl[tid + a];
                float s = (dn - (a == 0 ? DS_ : 0.f) + 1.f) * 0.5f * m_t * msk[tid + a];
                if (a < 8) o0[a] = f2bf(s); else o1[0] = f2bf(s);
            }
            unsigned short* dst = s16g + ((size_t)mb * T_ + t) * 16;
            *(ushort8_t*)dst = o0;
            *(ushort8_t*)(dst + 8) = o1;
        }
    }
}

// ===================== Kernel B: MFMA conv stack + masked GAP partials =====================
#define TT 128
#define G_ 16
#define WB 160            // TT + 2*G_
#define SBP 24            // sbuf pitch (48B rows: 16B-aligned, conflict-free)
#define OFF_BUFA 8192
#define OFF_BUFB 28672
#define OFF_MLD  49664
#define OFF_RED  50176
#define SMEM_TOT (OFF_RED + 1024)

// swizzled ushort index: 16B slot su (0..7) of row, XOR'd by row&7; off = ushort offset in slot
static __device__ __forceinline__ int swzi(int row, int su, int off) {
    return row * 64 + ((su ^ (row & 7)) << 3) + off;
}

template<int DIL>
static __device__ __forceinline__ void conv_stage(
    const unsigned short* __restrict__ wdg, const unsigned short* __restrict__ wpg,
    unsigned short* __restrict__ bufIn, unsigned short* __restrict__ bufOut,
    const float* __restrict__ b_d, const float* __restrict__ b_p,
    int t0, int l15, int lg, int mt0, int wn)
{
    // ---- dilated 3-tap conv as K=192 GEMM (k = tap*64 + ci), bufIn -> bufOut
    {
        bfrag ad[2][6];
        float bd[2][4];
        #pragma unroll
        for (int m = 0; m < 2; ++m) {
            int row = (mt0 + m) * 16 + l15;
            #pragma unroll
            for (int ks = 0; ks < 6; ++ks) {
                int tap = ks >> 1, half = ks & 1;
                ad[m][ks] = *(const bfrag*)(wdg + row * 192 + tap * 64 + half * 32 + lg * 8);
            }
            #pragma unroll
            for (int r = 0; r < 4; ++r) bd[m][r] = b_d[(mt0 + m) * 16 + lg * 4 + r];
        }
        for (int nt = wn * 5; nt < wn * 5 + 5; ++nt) {
            int j = nt * 16 + l15;
            f32x4 acc0 = {0.f, 0.f, 0.f, 0.f}, acc1 = {0.f, 0.f, 0.f, 0.f};
            #pragma unroll
            for (int ks = 0; ks < 6; ++ks) {
                int tap = ks >> 1, half = ks & 1;
                int brow = j + (tap - 1) * DIL;
                bfrag bv = *(const bfrag*)(bufIn + swzi(brow, half * 4 + lg, 0));
                acc0 = mfma_bf16(ad[0][ks], bv, acc0);
                acc1 = mfma_bf16(ad[1][ks], bv, acc1);
            }
            int tg = t0 - G_ + j;
            bool valid = (tg >= 0 && tg < T_);
            #pragma unroll
            for (int m = 0; m < 2; ++m) {
                f32x4 acc = m ? acc1 : acc0;
                ushort4_t pk;
                #pragma unroll
                for (int r = 0; r < 4; ++r) {
                    float v = acc[r] + bd[m][r];
                    v = valid ? fmaxf(v, 0.f) : 0.f;
                    pk[r] = f2bf(v);
                }
                *(ushort4_t*)(bufOut + swzi(j, (mt0 + m) * 2 + (lg >> 1), (lg & 1) * 4)) = pk;
            }
        }
    }
    __syncthreads();

    // ---- pointwise conv as K=64 GEMM, bufOut -> bufIn
    {
        bfrag ap[2][2];
        float bpv[2][4];
        #pragma unroll
        for (int m = 0; m < 2; ++m) {
            int row = (mt0 + m) * 16 + l15;
            #pragma unroll
            for (int half = 0; half < 2; ++half)
                ap[m][half] = *(const bfrag*)(wpg + row * 64 + half * 32 + lg * 8);
            #pragma unroll
            for (int r = 0; r < 4; ++r) bpv[m][r] = b_p[(mt0 + m) * 16 + lg * 4 + r];
        }
        for (int nt = wn * 5; nt < wn * 5 + 5; ++nt) {
            int j = nt * 16 + l15;
            f32x4 acc0 = {0.f, 0.f, 0.f, 0.f}, acc1 = {0.f, 0.f, 0.f, 0.f};
            #pragma unroll
            for (int half = 0; half < 2; ++half) {
                bfrag bv = *(const bfrag*)(bufOut + swzi(j, half * 4 + lg, 0));
                acc0 = mfma_bf16(ap[0][half], bv, acc0);
                acc1 = mfma_bf16(ap[1][half], bv, acc1);
            }
            int tg = t0 - G_ + j;
            bool valid = (tg >= 0 && tg < T_);
            #pragma unroll
            for (int m = 0; m < 2; ++m) {
                f32x4 acc = m ? acc1 : acc0;
                ushort4_t pk;
                #pragma unroll
                for (int r = 0; r < 4; ++r) {
                    float v = acc[r] + bpv[m][r];
                    v = valid ? fmaxf(v, 0.f) : 0.f;
                    pk[r] = f2bf(v);
                }
                *(ushort4_t*)(bufIn + swzi(j, (mt0 + m) * 2 + (lg >> 1), (lg & 1) * 4)) = pk;
            }
        }
    }
    __syncthreads();
}

__global__ __launch_bounds__(256, 3) void conv_mfma_kernel(
    const unsigned short* __restrict__ s16g,
    const float* __restrict__ mask0, const float* __restrict__ mask1,
    const unsigned short* __restrict__ wk,
    const float* __restrict__ b_in,
    const float* __restrict__ b_d1, const float* __restrict__ b_p1,
    const float* __restrict__ b_d2, const float* __restrict__ b_p2,
    const float* __restrict__ b_d3, const float* __restrict__ b_p3,
    float* __restrict__ z_part)        // [2*B][32][64]
{
    __shared__ __align__(16) char smem[SMEM_TOT];
    unsigned short* sbuf = (unsigned short*)smem;                 // [WB][SBP]
    unsigned short* bufA = (unsigned short*)(smem + OFF_BUFA);
    unsigned short* bufB = (unsigned short*)(smem + OFF_BUFB);
    float* mld = (float*)(smem + OFF_MLD);                        // [TT]
    float* red = (float*)(smem + OFF_RED);                        // [4][64]

    int bid  = blockIdx.x;                             // 2*B*32 = 2048
    int tile = bid & 31;
    int b    = (bid >> 5) & 31;
    int mod  = bid >> 10;
    int mb   = mod * B_ + b;
    const float* mask = mod ? mask1 : mask0;
    int t0  = tile * TT;
    int tid = threadIdx.x;
    int lane = tid & 63;
    int w = tid >> 6;
    int l15 = lane & 15, lg = lane >> 4;
    int wm = w >> 1, wn = w & 1;
    int mt0 = wm * 2;

    const unsigned short* weff_g = wk;

    // ---- stage s16 tile (with t-bounds zero fill) + mask
    {
        const unsigned short* srow = s16g + (size_t)mb * T_ * 16;
        for (int ch = tid; ch < WB * 2; ch += 256) {
            int j = ch >> 1, q = ch & 1;
            int t = t0 - G_ + j;
            ushort8_t v = {0, 0, 0, 0, 0, 0, 0, 0};
            if (t >= 0 && t < T_) v = *(const ushort8_t*)(srow + (size_t)t * 16 + q * 8);
            *(ushort8_t*)(sbuf + j * SBP + q * 8) = v;
        }
        if (tid < TT) {
            int tg = t0 + tid;
            mld[tid] = (tg < T_) ? mask[(size_t)b * T_ + tg] : 0.f;
        }
    }
    __syncthreads();

    // ---- in-conv (K=9 padded into one masked K=32 MFMA step) -> bufA
    {
        int lg2 = lg & 1;
        bfrag a_in[2];
        float bi[2][4];
        #pragma unroll
        for (int m = 0; m < 2; ++m) {
            int row = (mt0 + m) * 16 + l15;
            a_in[m] = *(const bfrag*)(weff_g + row * 16 + lg2 * 8);
            #pragma unroll
            for (int r = 0; r < 4; ++r) bi[m][r] = b_in[(mt0 + m) * 16 + lg * 4 + r];
        }
        for (int nt = wn * 5; nt < wn * 5 + 5; ++nt) {
            int j = nt * 16 + l15;
            bfrag bv = {0, 0, 0, 0, 0, 0, 0, 0};
            if (lg < 2) bv = *(const bfrag*)(sbuf + j * SBP + lg * 8);
            f32x4 acc0 = {0.f, 0.f, 0.f, 0.f}, acc1 = {0.f, 0.f, 0.f, 0.f};
            acc0 = mfma_bf16(a_in[0], bv, acc0);
            acc1 = mfma_bf16(a_in[1], bv, acc1);
            int tg = t0 - G_ + j;
            bool valid = (tg >= 0 && tg < T_);
            #pragma unroll
            for (int m = 0; m < 2; ++m) {
                f32x4 acc = m ? acc1 : acc0;
                ushort4_t pk;
                #pragma unroll
                for (int r = 0; r < 4; ++r) {
                    float v = acc[r] + bi[m][r];
                    v = valid ? fmaxf(v, 0.f) : 0.f;
                    pk[r] = f2bf(v);
                }
                *(ushort4_t*)(bufA + swzi(j, (mt0 + m) * 2 + (lg >> 1), (lg & 1) * 4)) = pk;
            }
        }
    }
    __syncthreads();

    conv_stage<1>(wk + 1024,             wk + 1024 + 12288,             bufA, bufB, b_d1, b_p1, t0, l15, lg, mt0, wn);
    conv_stage<2>(wk + 1024 + 16384,     wk + 1024 + 16384 + 12288,     bufA, bufB, b_d2, b_p2, t0, l15, lg, mt0, wn);
    conv_stage<4>(wk + 1024 + 2 * 16384, wk + 1024 + 2 * 16384 + 12288, bufA, bufB, b_d3, b_p3, t0, l15, lg, mt0, wn);

    // ---- masked GAP partial over this tile's 128 cols (j in [G_, G_+TT))
    {
        int c = tid & 63, g = tid >> 6;
        float acc = 0.f;
        #pragma unroll 4
        for (int i = 0; i < 32; ++i) {
            int jj = g * 32 + i;
            int r = G_ + jj;
            acc += bf2f(bufA[swzi(r, c >> 3, c & 7)]) * mld[jj];
        }
        red[g * 64 + c] = acc;
    }
    __syncthreads();
    if (tid < 64) {
        float z = red[tid] + red[64 + tid] + red[128 + tid] + red[192 + tid];
        z_part[((size_t)mb * 32 + tile) * 64 + tid] = z;
    }
}

// ===================== Kernel C: GAP divide + LayerNorm + gates =====================
__global__ __launch_bounds__(128) void gates_kernel(
    const float* __restrict__ z_part,
    const float* __restrict__ mask0, const float* __restrict__ mask1,
    const float* __restrict__ ln_g, const float* __restrict__ ln_b,
    const float* __restrict__ mha_w1, const float* __restrict__ mha_b1,
    const float* __restrict__ mha_w2, const float* __restrict__ mha_b2,
    const float* __restrict__ ffn_w1, const float* __restrict__ ffn_b1,
    const float* __restrict__ ffn_w2, const float* __restrict__ ffn_b2,
    float* __restrict__ out)
{
    __shared__ float fn[128];
    __shared__ float red[4];
    __shared__ float msum[2];
    int b = blockIdx.x, tid = threadIdx.x;
    int mod = tid >> 6, c = tid & 63;

    float z = 0.f;
    for (int tl = 0; tl < 32; ++tl)
        z += z_part[((size_t)(mod * B_ + b) * 32 + tl) * 64 + c];

    const float* mk = mod ? mask1 : mask0;
    float ms = 0.f;
    for (int t = c; t < T_; t += 64) ms += mk[(size_t)b * T_ + t];
    #pragma unroll
    for (int o = 32; o > 0; o >>= 1) ms += __shfl_xor(ms, o);
    if (c == 0) msum[mod] = ms;
    __syncthreads();

    float fv = z / (msum[mod] + EPSG);
    float s1 = fv, s2 = fv * fv;
    #pragma unroll
    for (int o = 32; o > 0; o >>= 1) { s1 += __shfl_xor(s1, o); s2 += __shfl_xor(s2, o); }
    if (c == 0) { red[mod * 2] = s1; red[mod * 2 + 1] = s2; }
    __syncthreads();

    float mu  = (red[0] + red[2]) * (1.0f / 128.0f);
    float ex2 = (red[1] + red[3]) * (1.0f / 128.0f);
    float var = ex2 - mu * mu;
    float fnv = (fv - mu) * rsqrtf(var + EPSL) * ln_g[tid] + ln_b[tid];
    fn[tid] = fnv;
    __syncthreads();

    const float* W1 = mod ? ffn_w1 : mha_w1;
    const float* B1 = mod ? ffn_b1 : mha_b1;
    const float* W2 = mod ? ffn_w2 : mha_w2;
    const float* B2 = mod ? ffn_b2 : mha_b2;
    float r = B1[c];
    for (int i = 0; i < 128; ++i) r += fn[i] * W1[i * 64 + c];
    r = fmaxf(r, 0.f);
    float g = r * W2[c];
    #pragma unroll
    for (int o = 32; o > 0; o >>= 1) g += __shfl_xor(g, o);
    if (c == 0) {
        g += B2[0];
        out[mod * B_ + b] = mod ? tanhf(g) : 1.0f / (1.0f + expf(-g));
    }
}

// ===================== launch =====================
extern "C" void kernel_launch(void* const* d_in, const int* in_sizes, int n_in,
                              void* d_out, int out_size, void* d_ws, size_t ws_size,
                              hipStream_t stream) {
    const float* video_feat = (const float*)d_in[0];
    const float* audio_feat = (const float*)d_in[1];
    const float* video_mask = (const float*)d_in[2];
    const float* audio_mask = (const float*)d_in[3];
    const float* w_in = (const float*)d_in[4];
    const float* b_in = (const float*)d_in[5];
    const float* w_d1 = (const float*)d_in[6];
    const float* b_d1 = (const float*)d_in[7];
    const float* w_p1 = (const float*)d_in[8];
    const float* b_p1 = (const float*)d_in[9];
    const float* w_d2 = (const float*)d_in[10];
    const float* b_d2 = (const float*)d_in[11];
    const float* w_p2 = (const float*)d_in[12];
    const float* b_p2 = (const float*)d_in[13];
    const float* w_d3 = (const float*)d_in[14];
    const float* b_d3 = (const float*)d_in[15];
    const float* w_p3 = (const float*)d_in[16];
    const float* b_p3 = (const float*)d_in[17];
    const float* ln_g = (const float*)d_in[18];
    const float* ln_b = (const float*)d_in[19];
    const float* mha_w1 = (const float*)d_in[20];
    const float* mha_b1 = (const float*)d_in[21];
    const float* mha_w2 = (const float*)d_in[22];
    const float* mha_b2 = (const float*)d_in[23];
    const float* ffn_w1 = (const float*)d_in[24];
    const float* ffn_b1 = (const float*)d_in[25];
    const float* ffn_w2 = (const float*)d_in[26];
    const float* ffn_b2 = (const float*)d_in[27];

    unsigned short* s16g = (unsigned short*)d_ws;                          // 2*B*T*16 bf16 = 8.39 MB
    float* z_part = (float*)((char*)d_ws + (size_t)2 * B_ * T_ * 16 * 2);  // 2*B*32*64 f32 = 512 KB
    unsigned short* wk = (unsigned short*)((char*)z_part + (size_t)2 * B_ * 32 * 64 * 4);  // 100 KB

    prepack_kernel<<<dim3(196), dim3(256), 0, stream>>>(
        w_in, w_d1, w_p1, w_d2, w_p2, w_d3, w_p3, wk);

    strip_kernel<<<dim3(2 * B_ * NT24), dim3(256), 0, stream>>>(
        audio_feat, audio_mask, video_feat, video_mask, s16g);

    conv_mfma_kernel<<<dim3(2 * B_ * (T_ / TT)), dim3(256), 0, stream>>>(
        s16g, audio_mask, video_mask, wk, b_in,
        b_d1, b_p1, b_d2, b_p2, b_d3, b_p3, z_part);

    gates_kernel<<<dim3(B_), dim3(128), 0, stream>>>(
        z_part, audio_mask, video_mask, ln_g, ln_b,
        mha_w1, mha_b1, mha_w2, mha_b2, ffn_w1, ffn_b1, ffn_w2, ffn_b2,
        (float*)d_out);
}

// Round 11
// 138.115 us; speedup vs baseline: 1.1772x; 1.0506x over previous
//
#include <hip/hip_runtime.h>
#include <math.h>

#define B_ 32
#define T_ 4096
#define D_ 256
#define C_ 64
#define EPSN 1e-6f
#define EPSG 1e-6f
#define EPSL 1e-5f
#define DS_ 0.1f

typedef short bfrag __attribute__((ext_vector_type(8)));      // 8 bf16 = 4 VGPR
typedef float f32x4 __attribute__((ext_vector_type(4)));
typedef unsigned short ushort4_t __attribute__((ext_vector_type(4)));
typedef unsigned short ushort8_t __attribute__((ext_vector_type(8)));

static __device__ __forceinline__ unsigned short f2bf(float f) {
    unsigned int u = __builtin_bit_cast(unsigned int, f);
    unsigned int r = u + 0x7fffu + ((u >> 16) & 1u);
    return (unsigned short)(r >> 16);
}
static __device__ __forceinline__ float bf2f(unsigned short u) {
    return __builtin_bit_cast(float, ((unsigned int)u) << 16);
}

static __device__ __forceinline__ f32x4 mfma_bf16(bfrag a, bfrag b, f32x4 c) {
    return __builtin_amdgcn_mfma_f32_16x16x32_bf16(a, b, c, 0, 0, 0);
}

static __device__ __forceinline__ bfrag cvt8(float4 lo, float4 hi) {
    bfrag v;
    v[0] = (short)f2bf(lo.x); v[1] = (short)f2bf(lo.y);
    v[2] = (short)f2bf(lo.z); v[3] = (short)f2bf(lo.w);
    v[4] = (short)f2bf(hi.x); v[5] = (short)f2bf(hi.y);
    v[6] = (short)f2bf(hi.z); v[7] = (short)f2bf(hi.w);
    return v;
}

// pack 2 f32 -> 2 bf16 (RNE) in one instruction: dst[15:0]=bf(a), dst[31:16]=bf(b)
static __device__ __forceinline__ unsigned int cvtpk(float a, float b) {
    unsigned int r;
    asm("v_cvt_pk_bf16_f32 %0, %1, %2" : "=v"(r) : "v"(a), "v"(b));
    return r;
}

// forced-issue 16B load: asm volatile keeps program order and pins the result registers
#define GLD16(dst, base, OFF) \
    asm volatile("global_load_dwordx4 %0, %1, off offset:" #OFF \
                 : "=v"(dst) : "v"(base))

// ===================== Kernel P: prepack weights -> bf16 fragment-layout images =====================
__global__ __launch_bounds__(256) void prepack_kernel(
    const float* __restrict__ w_in,
    const float* __restrict__ wd0, const float* __restrict__ wp0,
    const float* __restrict__ wd1, const float* __restrict__ wp1,
    const float* __restrict__ wd2, const float* __restrict__ wp2,
    unsigned short* __restrict__ wk)
{
    int idx = blockIdx.x * 256 + threadIdx.x;
    if (idx >= 1024 + 3 * 16384) return;
    if (idx < 1024) {
        int c = idx >> 4, a = idx & 15;
        float wv = 0.f;
        if (a <= 8) {
            wv = w_in[c * 17 + 8 + a];
            if (a > 0) wv += w_in[c * 17 + 8 - a];
        }
        wk[idx] = f2bf(wv);
    } else {
        int i2 = idx - 1024;
        int s = i2 >> 14;
        int r = i2 & 16383;
        const float* wd = s == 0 ? wd0 : (s == 1 ? wd1 : wd2);
        const float* wp = s == 0 ? wp0 : (s == 1 ? wp1 : wp2);
        unsigned short v;
        if (r < 12288) {
            int c = r / 192, k = r - c * 192;
            int tap = k >> 6, ci = k & 63;
            v = f2bf(wd[c * 192 + ci * 3 + tap]);
        } else {
            v = f2bf(wp[r - 12288]);
        }
        wk[idx] = v;
    }
}

// ===================== Kernel A: MFMA Gram-band strip, 3-tile diag, asm-forced deep MLP =====================
#define NT24 43            // ceil(4096 / 96) tiles per (mod,b)
#define DTP 18             // dotbuf pitch

__global__ __launch_bounds__(256, 2) void strip_kernel(
    const float* __restrict__ feat0, const float* __restrict__ mask0,
    const float* __restrict__ feat1, const float* __restrict__ mask1,
    unsigned short* __restrict__ s16g)     // [2*B][T][16] bf16, slots 0..8 = bands, 9..15 = 0
{
    __shared__ float dotbuf[4 * 3 * 16 * DTP];   // 13824 B
    __shared__ float scl[104];
    __shared__ float msk[104];

    int bid0 = blockIdx.x;                        // 2752 = 8 * 344
    int bid  = (bid0 & 7) * 344 + (bid0 >> 3);    // XCD-chunked bijective swizzle
    int tile = bid % NT24;
    int rem  = bid / NT24;
    int b    = rem & 31;
    int mod  = rem >> 5;
    int mb   = mod * B_ + b;
    const float* feat = mod ? feat1 : feat0;
    const float* mask = mod ? mask1 : mask0;
    int t0 = tile * 96;
    int tid = threadIdx.x;
    int w = tid >> 6, lane = tid & 63;
    int l15 = lane & 15, lg = lane >> 4;

    if (tid < 104) {
        int tg = t0 + tid;
        msk[tid] = (tg < T_) ? mask[(size_t)b * T_ + tg] : 0.f;
    }

    const float* fb = feat + (size_t)b * T_ * D_;

    // ---- per-wave 3-tile Gram group; 32 asm loads in flight before any convert
    {
        int i0 = t0 + 24 * w;
        int tA = i0 + l15;      if (tA >= T_) tA = 0;
        int tB = i0 + 16 + l15; if (tB >= T_) tB = 0;
        const float* pA = fb + (size_t)tA * D_ + lg * 8;
        const float* pB = fb + (size_t)tB * D_ + lg * 8;

        float4 fa[16], fbx[16];
        GLD16(fa[0],  pA, 0);    GLD16(fbx[0],  pB, 0);
        GLD16(fa[1],  pA, 16);   GLD16(fbx[1],  pB, 16);
        GLD16(fa[2],  pA, 128);  GLD16(fbx[2],  pB, 128);
        GLD16(fa[3],  pA, 144);  GLD16(fbx[3],  pB, 144);
        GLD16(fa[4],  pA, 256);  GLD16(fbx[4],  pB, 256);
        GLD16(fa[5],  pA, 272);  GLD16(fbx[5],  pB, 272);
        GLD16(fa[6],  pA, 384);  GLD16(fbx[6],  pB, 384);
        GLD16(fa[7],  pA, 400);  GLD16(fbx[7],  pB, 400);
        GLD16(fa[8],  pA, 512);  GLD16(fbx[8],  pB, 512);
        GLD16(fa[9],  pA, 528);  GLD16(fbx[9],  pB, 528);
        GLD16(fa[10], pA, 640);  GLD16(fbx[10], pB, 640);
        GLD16(fa[11], pA, 656);  GLD16(fbx[11], pB, 656);
        GLD16(fa[12], pA, 768);  GLD16(fbx[12], pB, 768);
        GLD16(fa[13], pA, 784);  GLD16(fbx[13], pB, 784);
        GLD16(fa[14], pA, 896);  GLD16(fbx[14], pB, 896);
        GLD16(fa[15], pA, 912);  GLD16(fbx[15], pB, 912);

        __builtin_amdgcn_sched_barrier(0);
        asm volatile("s_waitcnt vmcnt(0)" ::: "memory");
        __builtin_amdgcn_sched_barrier(0);

        f32x4 a00 = {0.f, 0.f, 0.f, 0.f};
        f32x4 a01 = {0.f, 0.f, 0.f, 0.f};
        f32x4 a11 = {0.f, 0.f, 0.f, 0.f};
        #pragma unroll
        for (int ks = 0; ks < 8; ++ks) {
            bfrag av = cvt8(fa[2 * ks], fa[2 * ks + 1]);
            bfrag bv = cvt8(fbx[2 * ks], fbx[2 * ks + 1]);
            a00 = mfma_bf16(av, av, a00);
            a01 = mfma_bf16(av, bv, a01);
            a11 = mfma_bf16(bv, bv, a11);
        }

        float* base = dotbuf + w * (3 * 16 * DTP);
        #pragma unroll
        for (int r = 0; r < 4; ++r) {
            int row = lg * 4 + r;
            base[row * DTP + l15] = a00[r];
            base[16 * DTP + row * DTP + l15] = a01[r];
            base[32 * DTP + row * DTP + l15] = a11[r];
        }
    }
    __syncthreads();

    // ---- scl[t] = m / (m*sqrt(selfdot) + eps) from T00/T11 diagonals
    if (tid < 104) {
        int ww = tid / 24; if (ww > 3) ww = 3;
        int v = tid - 24 * ww;
        const float* bb = dotbuf + ww * (3 * 16 * DTP);
        float sd = (v < 16) ? bb[v * DTP + v] : bb[32 * DTP + (v - 16) * DTP + (v - 16)];
        float m = msk[tid];
        scl[tid] = m / (m * sqrtf(sd) + EPSN);
    }
    __syncthreads();

    // ---- band extraction + bf16 pack (threads 0..95 = output rows)
    if (tid < 96) {
        int t = t0 + tid;
        if (t < T_) {
            int ww = tid / 24, r = tid - 24 * ww;
            const float* bb = dotbuf + ww * (3 * 16 * DTP);
            float m_t = msk[tid], sc_t = scl[tid];
            ushort8_t o0, o1;
            #pragma unroll
            for (int e = 0; e < 8; ++e) { o0[e] = 0; o1[e] = 0; }
            #pragma unroll
            for (int a = 0; a <= 8; ++a) {
                int c = r + a;
                float dot;
                if (r < 8)       dot = bb[r * DTP + c];
                else if (r < 16) dot = (c < 16) ? bb[r * DTP + c]
                                               : bb[16 * DTP + r * DTP + (c - 16)];
                else             dot = bb[32 * DTP + (r - 16) * DTP + (c - 16)];
                float dn = dot * sc_t * scl[tid + a];
                float s = (dn - (a == 0 ? DS_ : 0.f) + 1.f) * 0.5f * m_t * msk[tid + a];
                if (a < 8) o0[a] = f2bf(s); else o1[0] = f2bf(s);
            }
            unsigned short* dst = s16g + ((size_t)mb * T_ + t) * 16;
            *(ushort8_t*)dst = o0;
            *(ushort8_t*)(dst + 8) = o1;
        }
    }
}

// ===================== Kernel B: MFMA conv stack + masked GAP partials =====================
// LDS: red [0,1024) | bufA [1024, 21504) | bufB [21504, 41984) | 512B halo slack
#define TT 128
#define G_ 16
#define WB 160
#define OFF_BUFA 1024
#define OFF_BUFB 21504
#define SMEM_TOT (41984 + 512)

// swizzled ushort index: 16B slot su (0..7) of row, XOR'd by row&7; off = ushort offset in slot
static __device__ __forceinline__ int swzi(int row, int su, int off) {
    return row * 64 + ((su ^ (row & 7)) << 3) + off;
}

// epilogue: relu+mask, pack 4 f32 -> 4 bf16 via 2 cvt_pk, 8B store
static __device__ __forceinline__ void emit4(unsigned short* dst, f32x4 acc, bool valid) {
    float v0 = valid ? fmaxf(acc[0], 0.f) : 0.f;
    float v1 = valid ? fmaxf(acc[1], 0.f) : 0.f;
    float v2 = valid ? fmaxf(acc[2], 0.f) : 0.f;
    float v3 = valid ? fmaxf(acc[3], 0.f) : 0.f;
    uint2 p;
    p.x = cvtpk(v0, v1);
    p.y = cvtpk(v2, v3);
    *(uint2*)dst = p;
}

template<int DIL>
static __device__ __forceinline__ void conv_stage(
    const unsigned short* __restrict__ wdg, const unsigned short* __restrict__ wpg,
    unsigned short* __restrict__ bufIn, unsigned short* __restrict__ bufOut,
    const float* __restrict__ b_d, const float* __restrict__ b_p,
    int t0, int l15, int lg, int mt0, int wn)
{
    // ---- dilated 3-tap conv as K=192 GEMM (k = tap*64 + ci), bufIn -> bufOut
    {
        bfrag ad[2][6];
        f32x4 bd[2];
        #pragma unroll
        for (int m = 0; m < 2; ++m) {
            int row = (mt0 + m) * 16 + l15;
            #pragma unroll
            for (int ks = 0; ks < 6; ++ks) {
                int tap = ks >> 1, half = ks & 1;
                ad[m][ks] = *(const bfrag*)(wdg + row * 192 + tap * 64 + half * 32 + lg * 8);
            }
            #pragma unroll
            for (int r = 0; r < 4; ++r) bd[m][r] = b_d[(mt0 + m) * 16 + lg * 4 + r];
        }
        for (int nt = wn * 5; nt < wn * 5 + 5; ++nt) {
            int j = nt * 16 + l15;
            f32x4 acc0 = bd[0], acc1 = bd[1];      // bias folded into C-init
            #pragma unroll
            for (int ks = 0; ks < 6; ++ks) {
                int tap = ks >> 1, half = ks & 1;
                int brow = j + (tap - 1) * DIL;
                bfrag bv = *(const bfrag*)(bufIn + swzi(brow, half * 4 + lg, 0));
                acc0 = mfma_bf16(ad[0][ks], bv, acc0);
                acc1 = mfma_bf16(ad[1][ks], bv, acc1);
            }
            int tg = t0 - G_ + j;
            bool valid = (tg >= 0 && tg < T_);
            emit4(bufOut + swzi(j, (mt0 + 0) * 2 + (lg >> 1), (lg & 1) * 4), acc0, valid);
            emit4(bufOut + swzi(j, (mt0 + 1) * 2 + (lg >> 1), (lg & 1) * 4), acc1, valid);
        }
    }
    __syncthreads();

    // ---- pointwise conv as K=64 GEMM, bufOut -> bufIn
    {
        bfrag ap[2][2];
        f32x4 bp[2];
        #pragma unroll
        for (int m = 0; m < 2; ++m) {
            int row = (mt0 + m) * 16 + l15;
            #pragma unroll
            for (int half = 0; half < 2; ++half)
                ap[m][half] = *(const bfrag*)(wpg + row * 64 + half * 32 + lg * 8);
            #pragma unroll
            for (int r = 0; r < 4; ++r) bp[m][r] = b_p[(mt0 + m) * 16 + lg * 4 + r];
        }
        for (int nt = wn * 5; nt < wn * 5 + 5; ++nt) {
            int j = nt * 16 + l15;
            f32x4 acc0 = bp[0], acc1 = bp[1];
            #pragma unroll
            for (int half = 0; half < 2; ++half) {
                bfrag bv = *(const bfrag*)(bufOut + swzi(j, half * 4 + lg, 0));
                acc0 = mfma_bf16(ap[0][half], bv, acc0);
                acc1 = mfma_bf16(ap[1][half], bv, acc1);
            }
            int tg = t0 - G_ + j;
            bool valid = (tg >= 0 && tg < T_);
            emit4(bufIn + swzi(j, (mt0 + 0) * 2 + (lg >> 1), (lg & 1) * 4), acc0, valid);
            emit4(bufIn + swzi(j, (mt0 + 1) * 2 + (lg >> 1), (lg & 1) * 4), acc1, valid);
        }
    }
    __syncthreads();
}

__global__ __launch_bounds__(256, 3) void conv_mfma_kernel(
    const unsigned short* __restrict__ s16g,
    const float* __restrict__ mask0, const float* __restrict__ mask1,
    const unsigned short* __restrict__ wk,
    const float* __restrict__ b_in,
    const float* __restrict__ b_d1, const float* __restrict__ b_p1,
    const float* __restrict__ b_d2, const float* __restrict__ b_p2,
    const float* __restrict__ b_d3, const float* __restrict__ b_p3,
    float* __restrict__ z_part)        // [2*B][32][64]
{
    __shared__ __align__(16) char smem[SMEM_TOT];
    float* red = (float*)smem;                                    // [4][64]
    unsigned short* bufA = (unsigned short*)(smem + OFF_BUFA);
    unsigned short* bufB = (unsigned short*)(smem + OFF_BUFB);

    int bid  = blockIdx.x;                             // 2*B*32 = 2048
    int tile = bid & 31;
    int b    = (bid >> 5) & 31;
    int mod  = bid >> 10;
    int mb   = mod * B_ + b;
    const float* mask = mod ? mask1 : mask0;
    int t0  = tile * TT;
    int tid = threadIdx.x;
    int lane = tid & 63;
    int w = tid >> 6;
    int l15 = lane & 15, lg = lane >> 4;
    int wm = w >> 1, wn = w & 1;
    int mt0 = wm * 2;

    // ---- in-conv (K=9 padded into one masked K=32 MFMA step), s16 direct from global -> bufA
    {
        const unsigned short* srow = s16g + (size_t)mb * T_ * 16;
        int lg2 = lg & 1;
        bfrag a_in[2];
        f32x4 bi[2];
        #pragma unroll
        for (int m = 0; m < 2; ++m) {
            int row = (mt0 + m) * 16 + l15;
            a_in[m] = *(const bfrag*)(wk + row * 16 + lg2 * 8);
            #pragma unroll
            for (int r = 0; r < 4; ++r) bi[m][r] = b_in[(mt0 + m) * 16 + lg * 4 + r];
        }
        for (int nt = wn * 5; nt < wn * 5 + 5; ++nt) {
            int j = nt * 16 + l15;
            int tg = t0 - G_ + j;
            bool valid = (tg >= 0 && tg < T_);
            bfrag bv = {0, 0, 0, 0, 0, 0, 0, 0};
            if (lg < 2 && valid) bv = *(const bfrag*)(srow + (size_t)tg * 16 + lg * 8);
            f32x4 acc0 = bi[0], acc1 = bi[1];
            acc0 = mfma_bf16(a_in[0], bv, acc0);
            acc1 = mfma_bf16(a_in[1], bv, acc1);
            emit4(bufA + swzi(j, (mt0 + 0) * 2 + (lg >> 1), (lg & 1) * 4), acc0, valid);
            emit4(bufA + swzi(j, (mt0 + 1) * 2 + (lg >> 1), (lg & 1) * 4), acc1, valid);
        }
    }
    __syncthreads();

    conv_stage<1>(wk + 1024,             wk + 1024 + 12288,             bufA, bufB, b_d1, b_p1, t0, l15, lg, mt0, wn);
    conv_stage<2>(wk + 1024 + 16384,     wk + 1024 + 16384 + 12288,     bufA, bufB, b_d2, b_p2, t0, l15, lg, mt0, wn);
    conv_stage<4>(wk + 1024 + 2 * 16384, wk + 1024 + 2 * 16384 + 12288, bufA, bufB, b_d3, b_p3, t0, l15, lg, mt0, wn);

    // ---- masked GAP partial over this tile's 128 cols (j in [G_, G_+TT)); mask direct from global
    {
        int c = tid & 63, g = tid >> 6;
        const float* mrow = mask + (size_t)b * T_ + t0;
        float acc = 0.f;
        #pragma unroll 4
        for (int i = 0; i < 32; ++i) {
            int jj = g * 32 + i;
            int r = G_ + jj;
            acc += bf2f(bufA[swzi(r, c >> 3, c & 7)]) * mrow[jj];
        }
        red[g * 64 + c] = acc;
    }
    __syncthreads();
    if (tid < 64) {
        float z = red[tid] + red[64 + tid] + red[128 + tid] + red[192 + tid];
        z_part[((size_t)mb * 32 + tile) * 64 + tid] = z;
    }
}

// ===================== Kernel C: GAP divide + LayerNorm + gates =====================
__global__ __launch_bounds__(128) void gates_kernel(
    const float* __restrict__ z_part,
    const float* __restrict__ mask0, const float* __restrict__ mask1,
    const float* __restrict__ ln_g, const float* __restrict__ ln_b,
    const float* __restrict__ mha_w1, const float* __restrict__ mha_b1,
    const float* __restrict__ mha_w2, const float* __restrict__ mha_b2,
    const float* __restrict__ ffn_w1, const float* __restrict__ ffn_b1,
    const float* __restrict__ ffn_w2, const float* __restrict__ ffn_b2,
    float* __restrict__ out)
{
    __shared__ float fn[128];
    __shared__ float red[4];
    __shared__ float msum[2];
    int b = blockIdx.x, tid = threadIdx.x;
    int mod = tid >> 6, c = tid & 63;

    float z = 0.f;
    for (int tl = 0; tl < 32; ++tl)
        z += z_part[((size_t)(mod * B_ + b) * 32 + tl) * 64 + c];

    const float* mk = mod ? mask1 : mask0;
    float ms = 0.f;
    for (int t = c; t < T_; t += 64) ms += mk[(size_t)b * T_ + t];
    #pragma unroll
    for (int o = 32; o > 0; o >>= 1) ms += __shfl_xor(ms, o);
    if (c == 0) msum[mod] = ms;
    __syncthreads();

    float fv = z / (msum[mod] + EPSG);
    float s1 = fv, s2 = fv * fv;
    #pragma unroll
    for (int o = 32; o > 0; o >>= 1) { s1 += __shfl_xor(s1, o); s2 += __shfl_xor(s2, o); }
    if (c == 0) { red[mod * 2] = s1; red[mod * 2 + 1] = s2; }
    __syncthreads();

    float mu  = (red[0] + red[2]) * (1.0f / 128.0f);
    float ex2 = (red[1] + red[3]) * (1.0f / 128.0f);
    float var = ex2 - mu * mu;
    float fnv = (fv - mu) * rsqrtf(var + EPSL) * ln_g[tid] + ln_b[tid];
    fn[tid] = fnv;
    __syncthreads();

    const float* W1 = mod ? ffn_w1 : mha_w1;
    const float* B1 = mod ? ffn_b1 : mha_b1;
    const float* W2 = mod ? ffn_w2 : mha_w2;
    const float* B2 = mod ? ffn_b2 : mha_b2;
    float r = B1[c];
    for (int i = 0; i < 128; ++i) r += fn[i] * W1[i * 64 + c];
    r = fmaxf(r, 0.f);
    float g = r * W2[c];
    #pragma unroll
    for (int o = 32; o > 0; o >>= 1) g += __shfl_xor(g, o);
    if (c == 0) {
        g += B2[0];
        out[mod * B_ + b] = mod ? tanhf(g) : 1.0f / (1.0f + expf(-g));
    }
}

// ===================== launch =====================
extern "C" void kernel_launch(void* const* d_in, const int* in_sizes, int n_in,
                              void* d_out, int out_size, void* d_ws, size_t ws_size,
                              hipStream_t stream) {
    const float* video_feat = (const float*)d_in[0];
    const float* audio_feat = (const float*)d_in[1];
    const float* video_mask = (const float*)d_in[2];
    const float* audio_mask = (const float*)d_in[3];
    const float* w_in = (const float*)d_in[4];
    const float* b_in = (const float*)d_in[5];
    const float* w_d1 = (const float*)d_in[6];
    const float* b_d1 = (const float*)d_in[7];
    const float* w_p1 = (const float*)d_in[8];
    const float* b_p1 = (const float*)d_in[9];
    const float* w_d2 = (const float*)d_in[10];
    const float* b_d2 = (const float*)d_in[11];
    const float* w_p2 = (const float*)d_in[12];
    const float* b_p2 = (const float*)d_in[13];
    const float* w_d3 = (const float*)d_in[14];
    const float* b_d3 = (const float*)d_in[15];
    const float* w_p3 = (const float*)d_in[16];
    const float* b_p3 = (const float*)d_in[17];
    const float* ln_g = (const float*)d_in[18];
    const float* ln_b = (const float*)d_in[19];
    const float* mha_w1 = (const float*)d_in[20];
    const float* mha_b1 = (const float*)d_in[21];
    const float* mha_w2 = (const float*)d_in[22];
    const float* mha_b2 = (const float*)d_in[23];
    const float* ffn_w1 = (const float*)d_in[24];
    const float* ffn_b1 = (const float*)d_in[25];
    const float* ffn_w2 = (const float*)d_in[26];
    const float* ffn_b2 = (const float*)d_in[27];

    unsigned short* s16g = (unsigned short*)d_ws;                          // 2*B*T*16 bf16 = 8.39 MB
    float* z_part = (float*)((char*)d_ws + (size_t)2 * B_ * T_ * 16 * 2);  // 2*B*32*64 f32 = 512 KB
    unsigned short* wk = (unsigned short*)((char*)z_part + (size_t)2 * B_ * 32 * 64 * 4);  // 100 KB

    prepack_kernel<<<dim3(196), dim3(256), 0, stream>>>(
        w_in, w_d1, w_p1, w_d2, w_p2, w_d3, w_p3, wk);

    strip_kernel<<<dim3(2 * B_ * NT24), dim3(256), 0, stream>>>(
        audio_feat, audio_mask, video_feat, video_mask, s16g);

    conv_mfma_kernel<<<dim3(2 * B_ * (T_ / TT)), dim3(256), 0, stream>>>(
        s16g, audio_mask, video_mask, wk, b_in,
        b_d1, b_p1, b_d2, b_p2, b_d3, b_p3, z_part);

    gates_kernel<<<dim3(B_), dim3(128), 0, stream>>>(
        z_part, audio_mask, video_mask, ln_g, ln_b,
        mha_w1, mha_b1, mha_w2, mha_b2, ffn_w1, ffn_b1, ffn_w2, ffn_b2,
        (float*)d_out);
}